// Round 30
// baseline (633.717 us; speedup 1.0000x reference)
//
#include <hip/hip_runtime.h>
#include <hip/hip_bf16.h>

typedef __attribute__((ext_vector_type(8))) short short8;
typedef __attribute__((ext_vector_type(4))) float f32x4;

#define NB 32
#define NP 2048
#define NC 256
#define ND 128

// (1/sqrt(128)) * log2(e) folded into Wq/bq: logits land in log2 units
#define QSCALE (0.08838834764831845f * 1.4426950408889634f)
#define DEFER_THR 8.0f

__device__ inline float fast_exp2(float x){ return exp2f(x); }

// round-to-nearest-even fp32 -> bf16 bits (prep kernels only)
__device__ inline unsigned short f2bf(float f){
  union { float f; unsigned u; } v; v.f = f;
  unsigned r = v.u + 0x7FFFu + ((v.u >> 16) & 1u);
  return (unsigned short)(r >> 16);
}
__device__ inline unsigned pk2(float a, float b){
  return (unsigned)f2bf(a) | ((unsigned)f2bf(b) << 16);
}
// HW packed fp32x2 -> bf16x2; pure op, non-volatile
__device__ inline unsigned cvtpk(float a, float b){
  unsigned r;
  asm("v_cvt_pk_bf16_f32 %0, %1, %2" : "=v"(r) : "v"(a), "v"(b));
  return r;
}

// ---------------- K0: weight prep (transpose + scale + bf16) ----------------
__global__ __launch_bounds__(256) void prep_w(const float* __restrict__ Wq, const float* __restrict__ bq,
    const float* __restrict__ Wk, const float* __restrict__ bk,
    const float* __restrict__ Wv, const float* __restrict__ bv,
    unsigned short* __restrict__ WqkT, unsigned short* __restrict__ WvT, float* __restrict__ bqk){
  int o = blockIdx.x; int i = threadIdx.x;
  float wqk = (o < ND) ? Wq[i*ND + o] * QSCALE : Wk[i*ND + (o-ND)];
  WqkT[o*NC + i] = f2bf(wqk);
  WvT[o*NC + i]  = f2bf(Wv[i*NC + o]);
  if (i == 0) bqk[o] = (o < ND) ? bq[o]*QSCALE : bk[o-ND];
}

// ---------------- K1: FUSED projection (x staged once) ----------------
// 1024 blocks, 256 thr; block owns 64 x-rows. Part A: QK[row][256];
// Part B: VT[b][c][p] (transposed V). Both read the same Alds tile.
__global__ __launch_bounds__(256) void qkv_proj(const float* __restrict__ x,
    const unsigned short* __restrict__ WqkT, const float* __restrict__ bqk,
    const unsigned short* __restrict__ WvT, const float* __restrict__ bv,
    unsigned short* __restrict__ QK, unsigned short* __restrict__ VT){
  __shared__ unsigned short Alds[64*264];
  const int tid = threadIdx.x;
  const long rowbase = (long)blockIdx.x * 64;           // global x row base
  const int b = blockIdx.x >> 5, pt = blockIdx.x & 31;  // for VT addressing
  #pragma unroll
  for (int it = 0; it < 16; ++it){
    int chunk = tid + it*256;
    int r = chunk >> 6;
    int c4 = (chunk & 63) << 2;
    const float4 v = *(const float4*)(x + (rowbase + r)*NC + c4);
    *(uint2*)(&Alds[r*264 + c4]) = make_uint2(pk2(v.x, v.y), pk2(v.z, v.w));
  }
  __syncthreads();
  const int w = tid >> 6, lane = tid & 63, g = lane >> 4, c0 = lane & 15;
  const f32x4 zero = {0.f,0.f,0.f,0.f};

  // ---- Part A: QK (wave = 32 rows x 128 cols) ----
  {
    const int wrow = (w >> 1) * 32, wcol = (w & 1) * 128;
    f32x4 acc[2][8];
    #pragma unroll
    for (int m=0;m<2;m++){ for(int n=0;n<8;n++) acc[m][n] = zero; }
    #pragma unroll
    for (int ks=0; ks<8; ++ks){
      short8 a[2], bfr[8];
      #pragma unroll
      for (int m=0;m<2;m++)
        a[m] = *(const short8*)(&Alds[(wrow + 16*m + c0)*264 + ks*32 + 8*g]);
      #pragma unroll
      for (int n=0;n<8;n++)
        bfr[n] = *(const short8*)(&WqkT[(wcol + 16*n + c0)*NC + ks*32 + 8*g]);
      #pragma unroll
      for (int m=0;m<2;m++){
        #pragma unroll
        for(int n=0;n<8;n++)
          acc[m][n] = __builtin_amdgcn_mfma_f32_16x16x32_bf16(a[m], bfr[n], acc[m][n], 0,0,0);
      }
    }
    #pragma unroll
    for (int n=0;n<8;n++){
      int o = wcol + 16*n + c0;
      float bia = bqk[o];
      #pragma unroll
      for (int m=0;m<2;m++){
        long row = rowbase + wrow + 16*m + 4*g;
        #pragma unroll
        for (int r=0;r<4;r++)
          QK[(row + r)*NC + o] = f2bf(acc[m][n][r] + bia);
      }
    }
  }

  // ---- Part B: VT (wave = 128 c-rows x 32 p-cols) ----
  {
    const int wc = (w >> 1) * 128, wp = (w & 1) * 32;
    f32x4 acc[8][2];
    #pragma unroll
    for (int m=0;m<8;m++){ for(int n=0;n<2;n++) acc[m][n] = zero; }
    #pragma unroll
    for (int ks=0; ks<8; ++ks){
      short8 a[8], bb[2];
      #pragma unroll
      for (int m=0;m<8;m++)
        a[m] = *(const short8*)(&WvT[(wc + 16*m + c0)*NC + ks*32 + 8*g]);
      #pragma unroll
      for (int n=0;n<2;n++)
        bb[n] = *(const short8*)(&Alds[(wp + 16*n + c0)*264 + ks*32 + 8*g]);
      #pragma unroll
      for (int m=0;m<8;m++){
        #pragma unroll
        for(int n=0;n<2;n++)
          acc[m][n] = __builtin_amdgcn_mfma_f32_16x16x32_bf16(a[m], bb[n], acc[m][n], 0,0,0);
      }
    }
    #pragma unroll
    for (int m=0;m<8;m++){
      int cout = wc + 16*m + 4*g;
      #pragma unroll
      for (int r=0;r<4;r++){
        float bia = bv[cout + r];
        long base = ((long)b*NC + cout + r)*NP + pt*64 + wp;
        #pragma unroll
        for (int n=0;n<2;n++)
          VT[base + 16*n + c0] = f2bf(acc[m][n][r] + bia);
      }
    }
  }
}

// ---------------- K2: MFMA flash attention v6 (512 thr, P deduped) ----------------
// grid 512 (b*16 + qt), 8 waves; wave (wq,wc): 32 q x 128 ch; q-tile 128; KV tile 64.
// Plds shared per wq-pair: both wc waves write IDENTICAL bytes (same inputs/ops),
// each reads only rows it wrote itself -> benign race, no extra barrier.
// LDS = 16K (K) + 32K (V) + 18K (P) = 67584 B -> 2 blocks/CU = 16 waves/CU.
__global__ __launch_bounds__(512,4) void attn(const unsigned short* __restrict__ QK,
    const unsigned short* __restrict__ VT, const float* __restrict__ mask,
    float* __restrict__ out){
  __shared__ unsigned short Klds[64*128];    // XOR-swizzled rows (256B)
  __shared__ unsigned short Vlds[256*64];    // XOR-swizzled rows (128B)
  __shared__ unsigned short Plds[4*32*72];   // per-wq 32 q x 64 k (stride 72)
  const int tid = threadIdx.x;
  const int b = blockIdx.x >> 4, qt = blockIdx.x & 15;
  const int qbase = qt * 128;
  const int w = tid >> 6, lane = tid & 63, g = lane >> 4, c0 = lane & 15;
  const int wq = w >> 1, wc = w & 1;
  const int c07 = (c0 & 7) << 3;
  unsigned short* pw = &Plds[wq * 2304];

  const long qrow0 = (long)b * NP + qbase + wq*32;
  short8 qf[2][4];
  #pragma unroll
  for (int n2=0;n2<2;n2++)
    #pragma unroll
    for (int ks=0; ks<4; ++ks)
      qf[n2][ks] = *(const short8*)(&QK[(qrow0 + n2*16 + c0)*NC + ks*32 + 8*g]);

  const f32x4 zero = {0.f,0.f,0.f,0.f};
  f32x4 oacc[2][8];
  #pragma unroll
  for (int m2=0;m2<2;m2++){ for (int n=0;n<8;n++) oacc[m2][n] = zero; }
  float m_run[2] = {-1e30f, -1e30f}, l_run[2] = {0.f, 0.f};
  const long kvbase = (long)b * NP;
  const long vtbase = (long)b * NC * NP;

  short8 kreg[2], vreg[4];
  #pragma unroll
  for (int it=0; it<2; ++it){
    int chunk = tid + it*512;
    int key = chunk >> 4, s = chunk & 15;
    kreg[it] = *(const short8*)(&QK[(kvbase + key)*NC + ND + s*8]);
  }
  #pragma unroll
  for (int it=0; it<4; ++it){
    int chunk = tid + it*512;
    int c = chunk >> 3, s = chunk & 7;
    vreg[it] = *(const short8*)(&VT[vtbase + (long)c*NP + s*8]);
  }

  for (int t=0; t<32; ++t){
    __syncthreads();
    #pragma unroll
    for (int it=0; it<2; ++it){
      int chunk = tid + it*512;
      int key = chunk >> 4, s = chunk & 15;
      *(short8*)(&Klds[key*128 + ((s*8) ^ ((key&7)<<3))]) = kreg[it];
    }
    #pragma unroll
    for (int it=0; it<4; ++it){
      int chunk = tid + it*512;
      int c = chunk >> 3, s = chunk & 7;
      *(short8*)(&Vlds[c*64 + ((s*8) ^ ((c&7)<<3))]) = vreg[it];
    }
    __syncthreads();
    if (t + 1 < 32){
      const int kb1 = (t+1)*64;
      #pragma unroll
      for (int it=0; it<2; ++it){
        int chunk = tid + it*512;
        int key = chunk >> 4, s = chunk & 15;
        kreg[it] = *(const short8*)(&QK[(kvbase + kb1 + key)*NC + ND + s*8]);
      }
      #pragma unroll
      for (int it=0; it<4; ++it){
        int chunk = tid + it*512;
        int c = chunk >> 3, s = chunk & 7;
        vreg[it] = *(const short8*)(&VT[vtbase + (long)c*NP + kb1 + s*8]);
      }
    }

    // ---- QK^T: st[m][n2] = C[key=16m+4g+r][q=n2*16+c0] ----
    f32x4 st[4][2];
    #pragma unroll
    for (int m=0;m<4;m++){ st[m][0] = zero; st[m][1] = zero; }
    __builtin_amdgcn_s_setprio(1);
    #pragma unroll
    for (int ks=0;ks<4;ks++){
      short8 ka[4];
      #pragma unroll
      for (int m=0;m<4;m++)
        ka[m] = *(const short8*)(&Klds[(16*m + c0)*128 + ((ks*32 + 8*g) ^ c07)]);
      #pragma unroll
      for (int m=0;m<4;m++){
        st[m][0] = __builtin_amdgcn_mfma_f32_16x16x32_bf16(ka[m], qf[0][ks], st[m][0], 0,0,0);
        st[m][1] = __builtin_amdgcn_mfma_f32_16x16x32_bf16(ka[m], qf[1][ks], st[m][1], 0,0,0);
      }
    }
    __builtin_amdgcn_s_setprio(0);

    // ---- softmax per q-half; defer-max gates only the rescale ----
    #pragma unroll
    for (int n2=0;n2<2;n2++){
      float tm = st[0][n2][0];
      #pragma unroll
      for (int m=0;m<4;m++){
        #pragma unroll
        for (int r=0;r<4;r++) tm = fmaxf(tm, st[m][n2][r]);
      }
      tm = fmaxf(tm, __shfl_xor(tm, 16));
      tm = fmaxf(tm, __shfl_xor(tm, 32));
      if (!__all(tm <= m_run[n2] + DEFER_THR)){
        float mn = fmaxf(m_run[n2], tm);
        float alpha = fast_exp2(m_run[n2] - mn);
        l_run[n2] *= alpha;
        m_run[n2] = mn;
        float ar[4];
        #pragma unroll
        for (int r=0;r<4;r++) ar[r] = __shfl(alpha, 4*g + r);
        #pragma unroll
        for (int n=0;n<8;n++){
          #pragma unroll
          for (int r=0;r<4;r++) oacc[n2][n][r] *= ar[r];
        }
      }
      const float mr = m_run[n2];
      float psum = 0.f;
      #pragma unroll
      for (int m=0;m<4;m++){
        float p0 = fast_exp2(st[m][n2][0] - mr);
        float p1 = fast_exp2(st[m][n2][1] - mr);
        float p2 = fast_exp2(st[m][n2][2] - mr);
        float p3 = fast_exp2(st[m][n2][3] - mr);
        psum += (p0 + p1) + (p2 + p3);
        uint2 pd;
        pd.x = cvtpk(p0, p1);
        pd.y = cvtpk(p2, p3);
        *(uint2*)(&pw[(n2*16 + c0)*72 + 16*m + 4*g]) = pd;
      }
      psum += __shfl_xor(psum, 16);
      psum += __shfl_xor(psum, 32);
      l_run[n2] += psum;
    }

    // ---- PV ----
    __builtin_amdgcn_s_setprio(1);
    #pragma unroll
    for (int kk=0;kk<2;kk++){
      short8 pa[2];
      pa[0] = *(const short8*)(&pw[(c0     )*72 + kk*32 + 8*g]);
      pa[1] = *(const short8*)(&pw[(16 + c0)*72 + kk*32 + 8*g]);
      #pragma unroll
      for (int n=0;n<8;n++){
        short8 vb = *(const short8*)(&Vlds[(wc*128 + 16*n + c0)*64 + ((kk*32 + 8*g) ^ c07)]);
        oacc[0][n] = __builtin_amdgcn_mfma_f32_16x16x32_bf16(pa[0], vb, oacc[0][n], 0,0,0);
        oacc[1][n] = __builtin_amdgcn_mfma_f32_16x16x32_bf16(pa[1], vb, oacc[1][n], 0,0,0);
      }
    }
    __builtin_amdgcn_s_setprio(0);
  }

  // epilogue: /l, *mask, FP32 store
  #pragma unroll
  for (int m2=0;m2<2;m2++){
    float fac[4];
    #pragma unroll
    for (int r=0;r<4;r++){
      float lr = __shfl(l_run[m2], 4*g + r);
      long q = qbase + wq*32 + m2*16 + 4*g + r;
      fac[r] = mask[(long)b*NP + q] / lr;
    }
    #pragma unroll
    for (int n=0;n<8;n++){
      #pragma unroll
      for (int r=0;r<4;r++){
        long q = qbase + wq*32 + m2*16 + 4*g + r;
        out[((long)b*NP + q)*NC + wc*128 + 16*n + c0] = oacc[m2][n][r] * fac[r];
      }
    }
  }
}

extern "C" void kernel_launch(void* const* d_in, const int* in_sizes, int n_in,
                              void* d_out, int out_size, void* d_ws, size_t ws_size,
                              hipStream_t stream){
  const float* x    = (const float*)d_in[0];
  const float* mask = (const float*)d_in[1];
  const float* Wq   = (const float*)d_in[2];
  const float* bq   = (const float*)d_in[3];
  const float* Wk   = (const float*)d_in[4];
  const float* bk   = (const float*)d_in[5];
  const float* Wv   = (const float*)d_in[6];
  const float* bv   = (const float*)d_in[7];
  float* outp = (float*)d_out;
  char* ws = (char*)d_ws;

  // ws: QK 33554432 | VT 33554432 == 64 MiB. Prepped weights at head of d_out
  // (fp32, 67 MB); attn fully overwrites d_out afterwards (stream-ordered).
  unsigned short* QK   = (unsigned short*)(ws);
  unsigned short* VT   = (unsigned short*)(ws + 33554432);
  char* scratch        = (char*)d_out;
  unsigned short* WqkT = (unsigned short*)(scratch);            // 131072 B
  unsigned short* WvT  = (unsigned short*)(scratch + 131072);   // 131072 B
  float* bqk           = (float*)(scratch + 262144);            // 1024 B

  prep_w  <<<256, 256, 0, stream>>>(Wq, bq, Wk, bk, Wv, bv, WqkT, WvT, bqk);
  qkv_proj<<<1024, 256, 0, stream>>>(x, WqkT, bqk, WvT, bv, QK, VT);
  attn    <<<512, 512, 0, stream>>>(QK, VT, mask, outp);
}

// Round 31
// 275.093 us; speedup vs baseline: 2.3036x; 2.3036x over previous
//
#include <hip/hip_runtime.h>
#include <hip/hip_bf16.h>

typedef __attribute__((ext_vector_type(8))) short short8;
typedef __attribute__((ext_vector_type(4))) float f32x4;

#define NB 32
#define NP 2048
#define NC 256
#define ND 128

// (1/sqrt(128)) * log2(e) folded into Wq/bq: logits land in log2 units
#define QSCALE (0.08838834764831845f * 1.4426950408889634f)
#define DEFER_THR 8.0f

__device__ inline float fast_exp2(float x){ return exp2f(x); }

// round-to-nearest-even fp32 -> bf16 bits (prep kernels only)
__device__ inline unsigned short f2bf(float f){
  union { float f; unsigned u; } v; v.f = f;
  unsigned r = v.u + 0x7FFFu + ((v.u >> 16) & 1u);
  return (unsigned short)(r >> 16);
}
__device__ inline unsigned pk2(float a, float b){
  return (unsigned)f2bf(a) | ((unsigned)f2bf(b) << 16);
}
// HW packed fp32x2 -> bf16x2; pure op, non-volatile
__device__ inline unsigned cvtpk(float a, float b){
  unsigned r;
  asm("v_cvt_pk_bf16_f32 %0, %1, %2" : "=v"(r) : "v"(a), "v"(b));
  return r;
}

// ---------------- K0: weight prep (transpose + scale + bf16) ----------------
__global__ __launch_bounds__(256) void prep_w(const float* __restrict__ Wq, const float* __restrict__ bq,
    const float* __restrict__ Wk, const float* __restrict__ bk,
    const float* __restrict__ Wv, const float* __restrict__ bv,
    unsigned short* __restrict__ WqkT, unsigned short* __restrict__ WvT, float* __restrict__ bqk){
  int o = blockIdx.x; int i = threadIdx.x;
  float wqk = (o < ND) ? Wq[i*ND + o] * QSCALE : Wk[i*ND + (o-ND)];
  WqkT[o*NC + i] = f2bf(wqk);
  WvT[o*NC + i]  = f2bf(Wv[i*NC + o]);
  if (i == 0) bqk[o] = (o < ND) ? bq[o]*QSCALE : bk[o-ND];
}

// ---------------- K1: FUSED projection (x staged once) ----------------
__global__ __launch_bounds__(256) void qkv_proj(const float* __restrict__ x,
    const unsigned short* __restrict__ WqkT, const float* __restrict__ bqk,
    const unsigned short* __restrict__ WvT, const float* __restrict__ bv,
    unsigned short* __restrict__ QK, unsigned short* __restrict__ VT){
  __shared__ unsigned short Alds[64*264];
  const int tid = threadIdx.x;
  const long rowbase = (long)blockIdx.x * 64;
  const int b = blockIdx.x >> 5, pt = blockIdx.x & 31;
  #pragma unroll
  for (int it = 0; it < 16; ++it){
    int chunk = tid + it*256;
    int r = chunk >> 6;
    int c4 = (chunk & 63) << 2;
    const float4 v = *(const float4*)(x + (rowbase + r)*NC + c4);
    *(uint2*)(&Alds[r*264 + c4]) = make_uint2(pk2(v.x, v.y), pk2(v.z, v.w));
  }
  __syncthreads();
  const int w = tid >> 6, lane = tid & 63, g = lane >> 4, c0 = lane & 15;
  const f32x4 zero = {0.f,0.f,0.f,0.f};

  // ---- Part A: QK (wave = 32 rows x 128 cols) ----
  {
    const int wrow = (w >> 1) * 32, wcol = (w & 1) * 128;
    f32x4 acc[2][8];
    #pragma unroll
    for (int m=0;m<2;m++){ for(int n=0;n<8;n++) acc[m][n] = zero; }
    #pragma unroll
    for (int ks=0; ks<8; ++ks){
      short8 a[2], bfr[8];
      #pragma unroll
      for (int m=0;m<2;m++)
        a[m] = *(const short8*)(&Alds[(wrow + 16*m + c0)*264 + ks*32 + 8*g]);
      #pragma unroll
      for (int n=0;n<8;n++)
        bfr[n] = *(const short8*)(&WqkT[(wcol + 16*n + c0)*NC + ks*32 + 8*g]);
      #pragma unroll
      for (int m=0;m<2;m++){
        #pragma unroll
        for(int n=0;n<8;n++)
          acc[m][n] = __builtin_amdgcn_mfma_f32_16x16x32_bf16(a[m], bfr[n], acc[m][n], 0,0,0);
      }
    }
    #pragma unroll
    for (int n=0;n<8;n++){
      int o = wcol + 16*n + c0;
      float bia = bqk[o];
      #pragma unroll
      for (int m=0;m<2;m++){
        long row = rowbase + wrow + 16*m + 4*g;
        #pragma unroll
        for (int r=0;r<4;r++)
          QK[(row + r)*NC + o] = f2bf(acc[m][n][r] + bia);
      }
    }
  }

  // ---- Part B: VT (wave = 128 c-rows x 32 p-cols) ----
  {
    const int wc = (w >> 1) * 128, wp = (w & 1) * 32;
    f32x4 acc[8][2];
    #pragma unroll
    for (int m=0;m<8;m++){ for(int n=0;n<2;n++) acc[m][n] = zero; }
    #pragma unroll
    for (int ks=0; ks<8; ++ks){
      short8 a[8], bb[2];
      #pragma unroll
      for (int m=0;m<8;m++)
        a[m] = *(const short8*)(&WvT[(wc + 16*m + c0)*NC + ks*32 + 8*g]);
      #pragma unroll
      for (int n=0;n<2;n++)
        bb[n] = *(const short8*)(&Alds[(wp + 16*n + c0)*264 + ks*32 + 8*g]);
      #pragma unroll
      for (int m=0;m<8;m++){
        #pragma unroll
        for(int n=0;n<2;n++)
          acc[m][n] = __builtin_amdgcn_mfma_f32_16x16x32_bf16(a[m], bb[n], acc[m][n], 0,0,0);
      }
    }
    #pragma unroll
    for (int m=0;m<8;m++){
      int cout = wc + 16*m + 4*g;
      #pragma unroll
      for (int r=0;r<4;r++){
        float bia = bv[cout + r];
        long base = ((long)b*NC + cout + r)*NP + pt*64 + wp;
        #pragma unroll
        for (int n=0;n<2;n++)
          VT[base + 16*n + c0] = f2bf(acc[m][n][r] + bia);
      }
    }
  }
}

// ---------------- K2: MFMA flash attention v6b (512 thr, P deduped, 256-VGPR cap) ----------------
// grid 512 (b*16 + qt), 8 waves; wave (wq,wc): 32 q x 128 ch; q-tile 128; KV tile 64.
// LDS = 16K (K) + 32K (V) + 18K (P) = 67584 B -> up to 2 blocks/CU = 16 waves/CU
// (realized occupancy now set by VGPR ~120 -> 4 waves/SIMD possible).
__global__ __launch_bounds__(512,2) void attn(const unsigned short* __restrict__ QK,
    const unsigned short* __restrict__ VT, const float* __restrict__ mask,
    float* __restrict__ out){
  __shared__ unsigned short Klds[64*128];    // XOR-swizzled rows (256B)
  __shared__ unsigned short Vlds[256*64];    // XOR-swizzled rows (128B)
  __shared__ unsigned short Plds[4*32*72];   // per-wq 32 q x 64 k (stride 72)
  const int tid = threadIdx.x;
  const int b = blockIdx.x >> 4, qt = blockIdx.x & 15;
  const int qbase = qt * 128;
  const int w = tid >> 6, lane = tid & 63, g = lane >> 4, c0 = lane & 15;
  const int wq = w >> 1, wc = w & 1;
  const int c07 = (c0 & 7) << 3;
  unsigned short* pw = &Plds[wq * 2304];

  const long qrow0 = (long)b * NP + qbase + wq*32;
  short8 qf[2][4];
  #pragma unroll
  for (int n2=0;n2<2;n2++)
    #pragma unroll
    for (int ks=0; ks<4; ++ks)
      qf[n2][ks] = *(const short8*)(&QK[(qrow0 + n2*16 + c0)*NC + ks*32 + 8*g]);

  const f32x4 zero = {0.f,0.f,0.f,0.f};
  f32x4 oacc[2][8];
  #pragma unroll
  for (int m2=0;m2<2;m2++){ for (int n=0;n<8;n++) oacc[m2][n] = zero; }
  float m_run[2] = {-1e30f, -1e30f}, l_run[2] = {0.f, 0.f};
  const long kvbase = (long)b * NP;
  const long vtbase = (long)b * NC * NP;

  short8 kreg[2], vreg[4];
  #pragma unroll
  for (int it=0; it<2; ++it){
    int chunk = tid + it*512;
    int key = chunk >> 4, s = chunk & 15;
    kreg[it] = *(const short8*)(&QK[(kvbase + key)*NC + ND + s*8]);
  }
  #pragma unroll
  for (int it=0; it<4; ++it){
    int chunk = tid + it*512;
    int c = chunk >> 3, s = chunk & 7;
    vreg[it] = *(const short8*)(&VT[vtbase + (long)c*NP + s*8]);
  }

  for (int t=0; t<32; ++t){
    __syncthreads();
    #pragma unroll
    for (int it=0; it<2; ++it){
      int chunk = tid + it*512;
      int key = chunk >> 4, s = chunk & 15;
      *(short8*)(&Klds[key*128 + ((s*8) ^ ((key&7)<<3))]) = kreg[it];
    }
    #pragma unroll
    for (int it=0; it<4; ++it){
      int chunk = tid + it*512;
      int c = chunk >> 3, s = chunk & 7;
      *(short8*)(&Vlds[c*64 + ((s*8) ^ ((c&7)<<3))]) = vreg[it];
    }
    __syncthreads();
    if (t + 1 < 32){
      const int kb1 = (t+1)*64;
      #pragma unroll
      for (int it=0; it<2; ++it){
        int chunk = tid + it*512;
        int key = chunk >> 4, s = chunk & 15;
        kreg[it] = *(const short8*)(&QK[(kvbase + kb1 + key)*NC + ND + s*8]);
      }
      #pragma unroll
      for (int it=0; it<4; ++it){
        int chunk = tid + it*512;
        int c = chunk >> 3, s = chunk & 7;
        vreg[it] = *(const short8*)(&VT[vtbase + (long)c*NP + kb1 + s*8]);
      }
    }

    // ---- QK^T: st[m][n2] = C[key=16m+4g+r][q=n2*16+c0] ----
    f32x4 st[4][2];
    #pragma unroll
    for (int m=0;m<4;m++){ st[m][0] = zero; st[m][1] = zero; }
    __builtin_amdgcn_s_setprio(1);
    #pragma unroll
    for (int ks=0;ks<4;ks++){
      short8 ka[4];
      #pragma unroll
      for (int m=0;m<4;m++)
        ka[m] = *(const short8*)(&Klds[(16*m + c0)*128 + ((ks*32 + 8*g) ^ c07)]);
      #pragma unroll
      for (int m=0;m<4;m++){
        st[m][0] = __builtin_amdgcn_mfma_f32_16x16x32_bf16(ka[m], qf[0][ks], st[m][0], 0,0,0);
        st[m][1] = __builtin_amdgcn_mfma_f32_16x16x32_bf16(ka[m], qf[1][ks], st[m][1], 0,0,0);
      }
    }
    __builtin_amdgcn_s_setprio(0);

    // ---- softmax per q-half; defer-max gates only the rescale ----
    #pragma unroll
    for (int n2=0;n2<2;n2++){
      float tm = st[0][n2][0];
      #pragma unroll
      for (int m=0;m<4;m++){
        #pragma unroll
        for (int r=0;r<4;r++) tm = fmaxf(tm, st[m][n2][r]);
      }
      tm = fmaxf(tm, __shfl_xor(tm, 16));
      tm = fmaxf(tm, __shfl_xor(tm, 32));
      if (!__all(tm <= m_run[n2] + DEFER_THR)){
        float mn = fmaxf(m_run[n2], tm);
        float alpha = fast_exp2(m_run[n2] - mn);
        l_run[n2] *= alpha;
        m_run[n2] = mn;
        float ar[4];
        #pragma unroll
        for (int r=0;r<4;r++) ar[r] = __shfl(alpha, 4*g + r);
        #pragma unroll
        for (int n=0;n<8;n++){
          #pragma unroll
          for (int r=0;r<4;r++) oacc[n2][n][r] *= ar[r];
        }
      }
      const float mr = m_run[n2];
      float psum = 0.f;
      #pragma unroll
      for (int m=0;m<4;m++){
        float p0 = fast_exp2(st[m][n2][0] - mr);
        float p1 = fast_exp2(st[m][n2][1] - mr);
        float p2 = fast_exp2(st[m][n2][2] - mr);
        float p3 = fast_exp2(st[m][n2][3] - mr);
        psum += (p0 + p1) + (p2 + p3);
        uint2 pd;
        pd.x = cvtpk(p0, p1);
        pd.y = cvtpk(p2, p3);
        *(uint2*)(&pw[(n2*16 + c0)*72 + 16*m + 4*g]) = pd;
      }
      psum += __shfl_xor(psum, 16);
      psum += __shfl_xor(psum, 32);
      l_run[n2] += psum;
    }

    // ---- PV ----
    __builtin_amdgcn_s_setprio(1);
    #pragma unroll
    for (int kk=0;kk<2;kk++){
      short8 pa[2];
      pa[0] = *(const short8*)(&pw[(c0     )*72 + kk*32 + 8*g]);
      pa[1] = *(const short8*)(&pw[(16 + c0)*72 + kk*32 + 8*g]);
      #pragma unroll
      for (int n=0;n<8;n++){
        short8 vb = *(const short8*)(&Vlds[(wc*128 + 16*n + c0)*64 + ((kk*32 + 8*g) ^ c07)]);
        oacc[0][n] = __builtin_amdgcn_mfma_f32_16x16x32_bf16(pa[0], vb, oacc[0][n], 0,0,0);
        oacc[1][n] = __builtin_amdgcn_mfma_f32_16x16x32_bf16(pa[1], vb, oacc[1][n], 0,0,0);
      }
    }
    __builtin_amdgcn_s_setprio(0);
  }

  // epilogue: /l, *mask, FP32 store
  #pragma unroll
  for (int m2=0;m2<2;m2++){
    float fac[4];
    #pragma unroll
    for (int r=0;r<4;r++){
      float lr = __shfl(l_run[m2], 4*g + r);
      long q = qbase + wq*32 + m2*16 + 4*g + r;
      fac[r] = mask[(long)b*NP + q] / lr;
    }
    #pragma unroll
    for (int n=0;n<8;n++){
      #pragma unroll
      for (int r=0;r<4;r++){
        long q = qbase + wq*32 + m2*16 + 4*g + r;
        out[((long)b*NP + q)*NC + wc*128 + 16*n + c0] = oacc[m2][n][r] * fac[r];
      }
    }
  }
}

extern "C" void kernel_launch(void* const* d_in, const int* in_sizes, int n_in,
                              void* d_out, int out_size, void* d_ws, size_t ws_size,
                              hipStream_t stream){
  const float* x    = (const float*)d_in[0];
  const float* mask = (const float*)d_in[1];
  const float* Wq   = (const float*)d_in[2];
  const float* bq   = (const float*)d_in[3];
  const float* Wk   = (const float*)d_in[4];
  const float* bk   = (const float*)d_in[5];
  const float* Wv   = (const float*)d_in[6];
  const float* bv   = (const float*)d_in[7];
  float* outp = (float*)d_out;
  char* ws = (char*)d_ws;

  // ws: QK 33554432 | VT 33554432 == 64 MiB. Prepped weights at head of d_out
  // (fp32, 67 MB); attn fully overwrites d_out afterwards (stream-ordered).
  unsigned short* QK   = (unsigned short*)(ws);
  unsigned short* VT   = (unsigned short*)(ws + 33554432);
  char* scratch        = (char*)d_out;
  unsigned short* WqkT = (unsigned short*)(scratch);            // 131072 B
  unsigned short* WvT  = (unsigned short*)(scratch + 131072);   // 131072 B
  float* bqk           = (float*)(scratch + 262144);            // 1024 B

  prep_w  <<<256, 256, 0, stream>>>(Wq, bq, Wk, bk, Wv, bv, WqkT, WvT, bqk);
  qkv_proj<<<1024, 256, 0, stream>>>(x, WqkT, bqk, WvT, bv, QK, VT);
  attn    <<<512, 512, 0, stream>>>(QK, VT, mask, outp);
}

// Round 32
// 208.792 us; speedup vs baseline: 3.0352x; 1.3175x over previous
//
#include <hip/hip_runtime.h>
#include <hip/hip_bf16.h>

typedef __attribute__((ext_vector_type(8))) short short8;
typedef __attribute__((ext_vector_type(4))) float f32x4;
typedef unsigned int u32;
typedef __attribute__((address_space(3))) u32 lds_u32;
typedef const __attribute__((address_space(1))) u32 glb_u32;

#define NB 32
#define NP 2048
#define NC 256
#define ND 128

// (1/sqrt(128)) * log2(e) folded into Wq/bq: logits land in log2 units
#define QSCALE (0.08838834764831845f * 1.4426950408889634f)
#define DEFER_THR 8.0f

__device__ inline float fast_exp2(float x){ return exp2f(x); }

// round-to-nearest-even fp32 -> bf16 bits (prep kernels only)
__device__ inline unsigned short f2bf(float f){
  union { float f; unsigned u; } v; v.f = f;
  unsigned r = v.u + 0x7FFFu + ((v.u >> 16) & 1u);
  return (unsigned short)(r >> 16);
}
__device__ inline unsigned pk2(float a, float b){
  return (unsigned)f2bf(a) | ((unsigned)f2bf(b) << 16);
}
// HW packed fp32x2 -> bf16x2; pure op
__device__ inline unsigned cvtpk(float a, float b){
  unsigned r;
  asm("v_cvt_pk_bf16_f32 %0, %1, %2" : "=v"(r) : "v"(a), "v"(b));
  return r;
}

// ---------------- K0: weight prep (transpose + scale + bf16) ----------------
__global__ __launch_bounds__(256) void prep_w(const float* __restrict__ Wq, const float* __restrict__ bq,
    const float* __restrict__ Wk, const float* __restrict__ bk,
    const float* __restrict__ Wv, const float* __restrict__ bv,
    unsigned short* __restrict__ WqkT, unsigned short* __restrict__ WvT, float* __restrict__ bqk){
  int o = blockIdx.x; int i = threadIdx.x;
  float wqk = (o < ND) ? Wq[i*ND + o] * QSCALE : Wk[i*ND + (o-ND)];
  WqkT[o*NC + i] = f2bf(wqk);
  WvT[o*NC + i]  = f2bf(Wv[i*NC + o]);
  if (i == 0) bqk[o] = (o < ND) ? bq[o]*QSCALE : bk[o-ND];
}

// ---------------- K1: FUSED projection (x staged once) ----------------
__global__ __launch_bounds__(256) void qkv_proj(const float* __restrict__ x,
    const unsigned short* __restrict__ WqkT, const float* __restrict__ bqk,
    const unsigned short* __restrict__ WvT, const float* __restrict__ bv,
    unsigned short* __restrict__ QK, unsigned short* __restrict__ VT){
  __shared__ unsigned short Alds[64*264];
  const int tid = threadIdx.x;
  const long rowbase = (long)blockIdx.x * 64;
  const int b = blockIdx.x >> 5, pt = blockIdx.x & 31;
  #pragma unroll
  for (int it = 0; it < 16; ++it){
    int chunk = tid + it*256;
    int r = chunk >> 6;
    int c4 = (chunk & 63) << 2;
    const float4 v = *(const float4*)(x + (rowbase + r)*NC + c4);
    *(uint2*)(&Alds[r*264 + c4]) = make_uint2(pk2(v.x, v.y), pk2(v.z, v.w));
  }
  __syncthreads();
  const int w = tid >> 6, lane = tid & 63, g = lane >> 4, c0 = lane & 15;
  const f32x4 zero = {0.f,0.f,0.f,0.f};

  // ---- Part A: QK (wave = 32 rows x 128 cols) ----
  {
    const int wrow = (w >> 1) * 32, wcol = (w & 1) * 128;
    f32x4 acc[2][8];
    #pragma unroll
    for (int m=0;m<2;m++){ for(int n=0;n<8;n++) acc[m][n] = zero; }
    #pragma unroll
    for (int ks=0; ks<8; ++ks){
      short8 a[2], bfr[8];
      #pragma unroll
      for (int m=0;m<2;m++)
        a[m] = *(const short8*)(&Alds[(wrow + 16*m + c0)*264 + ks*32 + 8*g]);
      #pragma unroll
      for (int n=0;n<8;n++)
        bfr[n] = *(const short8*)(&WqkT[(wcol + 16*n + c0)*NC + ks*32 + 8*g]);
      #pragma unroll
      for (int m=0;m<2;m++){
        #pragma unroll
        for(int n=0;n<8;n++)
          acc[m][n] = __builtin_amdgcn_mfma_f32_16x16x32_bf16(a[m], bfr[n], acc[m][n], 0,0,0);
      }
    }
    #pragma unroll
    for (int n=0;n<8;n++){
      int o = wcol + 16*n + c0;
      float bia = bqk[o];
      #pragma unroll
      for (int m=0;m<2;m++){
        long row = rowbase + wrow + 16*m + 4*g;
        #pragma unroll
        for (int r=0;r<4;r++)
          QK[(row + r)*NC + o] = f2bf(acc[m][n][r] + bia);
      }
    }
  }

  // ---- Part B: VT (wave = 128 c-rows x 32 p-cols) ----
  {
    const int wc = (w >> 1) * 128, wp = (w & 1) * 32;
    f32x4 acc[8][2];
    #pragma unroll
    for (int m=0;m<8;m++){ for(int n=0;n<2;n++) acc[m][n] = zero; }
    #pragma unroll
    for (int ks=0; ks<8; ++ks){
      short8 a[8], bb[2];
      #pragma unroll
      for (int m=0;m<8;m++)
        a[m] = *(const short8*)(&WvT[(wc + 16*m + c0)*NC + ks*32 + 8*g]);
      #pragma unroll
      for (int n=0;n<2;n++)
        bb[n] = *(const short8*)(&Alds[(wp + 16*n + c0)*264 + ks*32 + 8*g]);
      #pragma unroll
      for (int m=0;m<8;m++){
        #pragma unroll
        for(int n=0;n<2;n++)
          acc[m][n] = __builtin_amdgcn_mfma_f32_16x16x32_bf16(a[m], bb[n], acc[m][n], 0,0,0);
      }
    }
    #pragma unroll
    for (int m=0;m<8;m++){
      int cout = wc + 16*m + 4*g;
      #pragma unroll
      for (int r=0;r<4;r++){
        float bia = bv[cout + r];
        long base = ((long)b*NC + cout + r)*NP + pt*64 + wp;
        #pragma unroll
        for (int n=0;n<2;n++)
          VT[base + 16*n + c0] = f2bf(acc[m][n][r] + bia);
      }
    }
  }
}

// ---------------- K2: MFMA flash attention v7 ----------------
// grid 512 (b*16 + qt), 4 waves; wave owns 32 q x FULL 256 ch (no wc dup).
// K/V staged via global_load_lds with pre-swizzled SOURCE (linear LDS dest);
// read side keeps the XOR swizzle. LDS = 16K + 32K + 18K = 67584 -> 2 blk/CU.
__global__ __launch_bounds__(256,2) void attn(const unsigned short* __restrict__ QK,
    const unsigned short* __restrict__ VT, const float* __restrict__ mask,
    float* __restrict__ out){
  __shared__ unsigned short Klds[64*128];    // swizzled via source pre-XOR
  __shared__ unsigned short Vlds[256*64];
  __shared__ unsigned short Plds[4*32*72];   // per-wave 32 q x 64 k (stride 72)
  const int tid = threadIdx.x;
  const int b = blockIdx.x >> 4, qt = blockIdx.x & 15;
  const int qbase = qt * 128;
  const int w = tid >> 6, lane = tid & 63, g = lane >> 4, c0 = lane & 15;
  const int c07 = (c0 & 7) << 3;
  unsigned short* pw = &Plds[w * 2304];

  const long qrow0 = (long)b * NP + qbase + w*32;
  short8 qf[2][4];
  #pragma unroll
  for (int n2=0;n2<2;n2++)
    #pragma unroll
    for (int ks=0; ks<4; ++ks)
      qf[n2][ks] = *(const short8*)(&QK[(qrow0 + n2*16 + c0)*NC + ks*32 + 8*g]);

  const f32x4 zero = {0.f,0.f,0.f,0.f};
  f32x4 oacc[2][16];
  #pragma unroll
  for (int n2=0;n2<2;n2++){ for (int n=0;n<16;n++) oacc[n2][n] = zero; }
  float m_run[2] = {-1e30f, -1e30f}, l_run[2] = {0.f, 0.f};
  const long kvbase = (long)b * NP;
  const long vtbase = (long)b * NC * NP;

  for (int t=0; t<32; ++t){
    const int kb = t*64;
    __syncthreads();                        // previous tile fully consumed
    // K tile 64x128: 4 gload_lds per wave. chunk c -> key=c>>4, slot s'=c&15;
    // source slot = s' ^ (key&7) (inverse-XOR at source, linear LDS dest).
    #pragma unroll
    for (int j=0;j<4;++j){
      int chunk = w*256 + j*64 + lane;
      int key = chunk >> 4, sp = chunk & 15;
      const unsigned short* src = &QK[(kvbase + kb + key)*NC + ND + ((sp ^ (key&7))*8)];
      __builtin_amdgcn_global_load_lds((glb_u32*)src, (lds_u32*)&Klds[(w*256 + j*64)*8], 16, 0, 0);
    }
    // V tile 256x64: 8 gload_lds per wave. chunk c -> crow=c>>3, s'=c&7.
    #pragma unroll
    for (int j=0;j<8;++j){
      int chunk = w*512 + j*64 + lane;
      int crow = chunk >> 3, sp = chunk & 7;
      const unsigned short* src = &VT[vtbase + (long)crow*NP + kb + ((sp ^ (crow&7))*8)];
      __builtin_amdgcn_global_load_lds((glb_u32*)src, (lds_u32*)&Vlds[(w*512 + j*64)*8], 16, 0, 0);
    }
    __syncthreads();                        // drains vmcnt -> tile t ready

    // ---- QK^T: st[m][n2] = C[key=16m+4g+r][q=n2*16+c0] ----
    f32x4 st[4][2];
    #pragma unroll
    for (int m=0;m<4;m++){ st[m][0] = zero; st[m][1] = zero; }
    __builtin_amdgcn_s_setprio(1);
    #pragma unroll
    for (int ks=0;ks<4;ks++){
      short8 ka[4];
      #pragma unroll
      for (int m=0;m<4;m++)
        ka[m] = *(const short8*)(&Klds[(16*m + c0)*128 + ((ks*32 + 8*g) ^ c07)]);
      #pragma unroll
      for (int m=0;m<4;m++){
        st[m][0] = __builtin_amdgcn_mfma_f32_16x16x32_bf16(ka[m], qf[0][ks], st[m][0], 0,0,0);
        st[m][1] = __builtin_amdgcn_mfma_f32_16x16x32_bf16(ka[m], qf[1][ks], st[m][1], 0,0,0);
      }
    }
    __builtin_amdgcn_s_setprio(0);

    // ---- softmax per q-half; defer-max gates only the rescale ----
    #pragma unroll
    for (int n2=0;n2<2;n2++){
      float tm = st[0][n2][0];
      #pragma unroll
      for (int m=0;m<4;m++){
        #pragma unroll
        for (int r=0;r<4;r++) tm = fmaxf(tm, st[m][n2][r]);
      }
      tm = fmaxf(tm, __shfl_xor(tm, 16));
      tm = fmaxf(tm, __shfl_xor(tm, 32));
      if (!__all(tm <= m_run[n2] + DEFER_THR)){
        float mn = fmaxf(m_run[n2], tm);
        float alpha = fast_exp2(m_run[n2] - mn);
        l_run[n2] *= alpha;
        m_run[n2] = mn;
        float ar[4];
        #pragma unroll
        for (int r=0;r<4;r++) ar[r] = __shfl(alpha, 4*g + r);
        #pragma unroll
        for (int n=0;n<16;n++){
          #pragma unroll
          for (int r=0;r<4;r++) oacc[n2][n][r] *= ar[r];
        }
      }
      const float mr = m_run[n2];
      float psum = 0.f;
      #pragma unroll
      for (int m=0;m<4;m++){
        float p0 = fast_exp2(st[m][n2][0] - mr);
        float p1 = fast_exp2(st[m][n2][1] - mr);
        float p2 = fast_exp2(st[m][n2][2] - mr);
        float p3 = fast_exp2(st[m][n2][3] - mr);
        psum += (p0 + p1) + (p2 + p3);
        uint2 pd;
        pd.x = cvtpk(p0, p1);
        pd.y = cvtpk(p2, p3);
        *(uint2*)(&pw[(n2*16 + c0)*72 + 16*m + 4*g]) = pd;
      }
      psum += __shfl_xor(psum, 16);
      psum += __shfl_xor(psum, 32);
      l_run[n2] += psum;
    }

    // ---- PV over all 256 channels ----
    __builtin_amdgcn_s_setprio(1);
    #pragma unroll
    for (int kk=0;kk<2;kk++){
      short8 pa[2];
      pa[0] = *(const short8*)(&pw[(c0     )*72 + kk*32 + 8*g]);
      pa[1] = *(const short8*)(&pw[(16 + c0)*72 + kk*32 + 8*g]);
      #pragma unroll
      for (int n=0;n<16;n++){
        short8 vb = *(const short8*)(&Vlds[(16*n + c0)*64 + ((kk*32 + 8*g) ^ c07)]);
        oacc[0][n] = __builtin_amdgcn_mfma_f32_16x16x32_bf16(pa[0], vb, oacc[0][n], 0,0,0);
        oacc[1][n] = __builtin_amdgcn_mfma_f32_16x16x32_bf16(pa[1], vb, oacc[1][n], 0,0,0);
      }
    }
    __builtin_amdgcn_s_setprio(0);
  }

  // epilogue: /l, *mask, FP32 store
  #pragma unroll
  for (int n2=0;n2<2;n2++){
    float fac[4];
    #pragma unroll
    for (int r=0;r<4;r++){
      float lr = __shfl(l_run[n2], 4*g + r);
      long q = qbase + w*32 + n2*16 + 4*g + r;
      fac[r] = mask[(long)b*NP + q] / lr;
    }
    #pragma unroll
    for (int n=0;n<16;n++){
      #pragma unroll
      for (int r=0;r<4;r++){
        long q = qbase + w*32 + n2*16 + 4*g + r;
        out[((long)b*NP + q)*NC + 16*n + c0] = oacc[n2][n][r] * fac[r];
      }
    }
  }
}

extern "C" void kernel_launch(void* const* d_in, const int* in_sizes, int n_in,
                              void* d_out, int out_size, void* d_ws, size_t ws_size,
                              hipStream_t stream){
  const float* x    = (const float*)d_in[0];
  const float* mask = (const float*)d_in[1];
  const float* Wq   = (const float*)d_in[2];
  const float* bq   = (const float*)d_in[3];
  const float* Wk   = (const float*)d_in[4];
  const float* bk   = (const float*)d_in[5];
  const float* Wv   = (const float*)d_in[6];
  const float* bv   = (const float*)d_in[7];
  float* outp = (float*)d_out;
  char* ws = (char*)d_ws;

  // ws: QK 33554432 | VT 33554432 == 64 MiB. Prepped weights at head of d_out
  // (fp32, 67 MB); attn fully overwrites d_out afterwards (stream-ordered).
  unsigned short* QK   = (unsigned short*)(ws);
  unsigned short* VT   = (unsigned short*)(ws + 33554432);
  char* scratch        = (char*)d_out;
  unsigned short* WqkT = (unsigned short*)(scratch);            // 131072 B
  unsigned short* WvT  = (unsigned short*)(scratch + 131072);   // 131072 B
  float* bqk           = (float*)(scratch + 262144);            // 1024 B

  prep_w  <<<256, 256, 0, stream>>>(Wq, bq, Wk, bk, Wv, bv, WqkT, WvT, bqk);
  qkv_proj<<<1024, 256, 0, stream>>>(x, WqkT, bqk, WvT, bv, QK, VT);
  attn    <<<512, 256, 0, stream>>>(QK, VT, mask, outp);
}